// Round 2
// 394.260 us; speedup vs baseline: 1.0279x; 1.0279x over previous
//
#include <hip/hip_runtime.h>

// MakeCutouts: out[(n*B+b), c, i, j] = x[b, c, oy[n] + i*sz[n]/224, ox[n] + j*sz[n]/224]
// B=16, C=3, H=W=512, CUTN=32, CUT_SIZE=224. Output fp32, 308 MB -> write-bound target.
//
// Per wave-task (one (n,b,c) group x 56-row chunk): stage each 2KB input row to
// LDS via global_load_lds (coalesced 16B/lane), gather with 4 ds_read_b32
// (lane stride 1-2.3 floats -> <=2-way bank conflict, free), store coalesced
// dwords. Depth-3 rotating buffers, counted vmcnt.
//
// SYNC RULE (fix for round-1 failure): vmcnt(N) with N = #loads issued AFTER
// the load group we need. Safe regardless of store retirement order: if the
// needed loads were outstanding, in-order LOAD retirement implies all N newer
// loads are outstanding too -> count >= N+2 > N -> wait couldn't have passed.
// Round-1's N=6 mixed store counts into N, which under-waits if stores retire
// early. Stores can now only cause over-wait (and the stage-before-stores
// ordering keeps the newest stores out of the wait's drain set).

#define CUT_SIZE 224
#define CUTN     32
#define BATCH    16
#define CHAN     3
#define HEIGHT   512
#define WIDTH    512
#define GROUPS   (CUTN * BATCH * CHAN)   // 1536 (n,b,c) groups
#define I_PER_WAVE 56
#define CHUNKS   (CUT_SIZE / I_PER_WAVE) // 4
#define WPB      4                        // waves per block
#define DEPTH    3                        // pipeline depth (rows in flight)

typedef const __attribute__((address_space(1))) void* gas_ptr;
typedef __attribute__((address_space(3))) void*       las_ptr;

__device__ __forceinline__ void stage_row(const float* src_row, float* lds_buf, int lane)
{
    // Stage 2048 B (one full input row): 2 x (64 lanes x 16 B).
    // LDS dest is wave-uniform base + lane*16 (HW rule); global src is per-lane.
    __builtin_amdgcn_global_load_lds((gas_ptr)(src_row + lane * 4),
                                     (las_ptr)(lds_buf), 16, 0, 0);
    __builtin_amdgcn_global_load_lds((gas_ptr)(src_row + 256 + lane * 4),
                                     (las_ptr)(lds_buf + 256), 16, 0, 0);
}

__global__ __launch_bounds__(256) void make_cutouts_kernel(
    const float* __restrict__ x,
    const int*   __restrict__ sizes,
    const int*   __restrict__ offsetx,
    const int*   __restrict__ offsety,
    float*       __restrict__ out)
{
    __shared__ __align__(16) float lds[WPB][DEPTH][WIDTH];   // 24 KB/block -> 6 blocks/CU

    const int wid  = threadIdx.x >> 6;
    const int lane = threadIdx.x & 63;

    const int task  = blockIdx.x * WPB + wid;   // 0..6143
    const int g     = task >> 2;                // (n,b,c) group, 0..1535
    const int chunk = task & 3;                 // which 56-row slice

    const int c  = g % CHAN;
    const int tb = g / CHAN;
    const int b  = tb % BATCH;
    const int n  = tb / BATCH;

    const int sz = sizes[n];
    const int ox = offsetx[n];
    const int oy = offsety[n];

    const float* img  = x + (size_t)(b * CHAN + c) * (HEIGHT * WIDTH);
    float*       outg = out + (size_t)g * (CUT_SIZE * CUT_SIZE)
                            + (size_t)(chunk * I_PER_WAVE) * CUT_SIZE;

    // Per-lane gather x-offsets: invariant across i (depend only on n, lane).
    const unsigned usz = (unsigned)sz;
    const int xi0 = ox + (int)(((unsigned)(lane      ) * usz) / CUT_SIZE);
    const int xi1 = ox + (int)(((unsigned)(lane +  64) * usz) / CUT_SIZE);
    const int xi2 = ox + (int)(((unsigned)(lane + 128) * usz) / CUT_SIZE);
    const int xi3 = (lane < 32)
                  ? ox + (int)(((unsigned)(lane + 192) * usz) / CUT_SIZE)
                  : xi0;   // clamped: value unused for lane>=32, keeps LDS read in-bounds

    float* p0 = &lds[wid][0][0];   // holds row k   (at iteration k)
    float* p1 = &lds[wid][1][0];   // holds row k+1
    float* p2 = &lds[wid][2][0];   // holds row k+2

    const int ibase = chunk * I_PER_WAVE;

    #define ROW_PTR(K) (img + (size_t)(oy + (int)(((unsigned)((ibase + (K)) * sz)) / CUT_SIZE)) * WIDTH)

    // Prologue: stage rows 0,1,2 (6 loads outstanding).
    stage_row(ROW_PTR(0), p0, lane);
    stage_row(ROW_PTR(1), p1, lane);
    stage_row(ROW_PTR(2), p2, lane);

    for (int k = 0; k < I_PER_WAVE; ++k) {
        // Before gather(k): loads newer than row k's = rows (k+1..min(k+2,55)),
        // i.e. 4 in steady state, 2 / 0 in the 2-iteration tail.
        if      (k <  I_PER_WAVE - 2) { asm volatile("s_waitcnt vmcnt(4)" ::: "memory"); }
        else if (k == I_PER_WAVE - 2) { asm volatile("s_waitcnt vmcnt(2)" ::: "memory"); }
        else                          { asm volatile("s_waitcnt vmcnt(0)" ::: "memory"); }
        __builtin_amdgcn_sched_barrier(0);

        const float v0 = p0[xi0];
        const float v1 = p0[xi1];
        const float v2 = p0[xi2];
        const float v3 = p0[xi3];

        // Drain the ds_reads (data safely in VGPRs) before the DMA restage
        // overwrites p0's buffer; sched_barrier pins the order (rule #18).
        asm volatile("s_waitcnt lgkmcnt(0)" ::: "memory");
        __builtin_amdgcn_sched_barrier(0);

        // Restage p0's buffer with row k+3. Issued BEFORE the stores so the
        // newest ops at the next wait are stores -> they stay in flight.
        if (k + DEPTH < I_PER_WAVE) {
            stage_row(ROW_PTR(k + DEPTH), p0, lane);
        }

        float* orow = outg + (size_t)k * CUT_SIZE;
        orow[lane      ] = v0;
        orow[lane +  64] = v1;
        orow[lane + 128] = v2;
        if (lane < 32) orow[lane + 192] = v3;

        // Rotate: p0<-row k+1, p1<-row k+2, p2<-row k+3 (just staged).
        float* t = p0; p0 = p1; p1 = p2; p2 = t;
    }
    #undef ROW_PTR
}

extern "C" void kernel_launch(void* const* d_in, const int* in_sizes, int n_in,
                              void* d_out, int out_size, void* d_ws, size_t ws_size,
                              hipStream_t stream) {
    const float* x       = (const float*)d_in[0];
    const int*   sizes   = (const int*)d_in[1];
    const int*   offsetx = (const int*)d_in[2];
    const int*   offsety = (const int*)d_in[3];
    float*       out     = (float*)d_out;

    const int grid = GROUPS * CHUNKS / WPB;   // 1536 blocks x 256 threads
    make_cutouts_kernel<<<grid, 256, 0, stream>>>(x, sizes, offsetx, offsety, out);
}